// Round 1
// baseline (1000.432 us; speedup 1.0000x reference)
//
#include <hip/hip_runtime.h>
#include <hip/hip_bf16.h>

#define N_NODES 50000
#define N_EDGES 1200000
#define DIM 64

// ---------------- histogram: out-degree (by u) for norm, in-degree (by v) for CSR
__global__ void k_hist(const int* __restrict__ ei, int* __restrict__ degu, int* __restrict__ cnt) {
    int e = blockIdx.x * 256 + threadIdx.x;
    if (e < N_EDGES) {
        atomicAdd(&degu[ei[e]], 1);
        atomicAdd(&cnt[ei[N_EDGES + e]], 1);
    }
}

// ---------------- dis = (deg_u + 1)^-0.5
__global__ void k_dis(const int* __restrict__ degu, float* __restrict__ dis) {
    int n = blockIdx.x * 256 + threadIdx.x;
    if (n < N_NODES) dis[n] = rsqrtf((float)degu[n] + 1.0f);
}

// ---------------- 2-level exclusive scan of cnt -> row_ptr
// scan1: 1024 threads x 4 elems = 4096 per block, 13 blocks
__global__ __launch_bounds__(1024) void k_scan1(const int* __restrict__ cnt,
                                                int* __restrict__ row_ptr,
                                                int* __restrict__ bsums) {
    __shared__ int sd[1024];
    int t = threadIdx.x;
    int base = blockIdx.x * 4096 + t * 4;
    int v0 = (base + 0 < N_NODES) ? cnt[base + 0] : 0;
    int v1 = (base + 1 < N_NODES) ? cnt[base + 1] : 0;
    int v2 = (base + 2 < N_NODES) ? cnt[base + 2] : 0;
    int v3 = (base + 3 < N_NODES) ? cnt[base + 3] : 0;
    int p0 = 0, p1 = v0, p2 = v0 + v1, p3 = v0 + v1 + v2;
    int tot = p3 + v3;
    sd[t] = tot;
    __syncthreads();
    for (int off = 1; off < 1024; off <<= 1) {
        int x = 0;
        if (t >= off) x = sd[t - off];
        __syncthreads();
        sd[t] += x;
        __syncthreads();
    }
    int excl = sd[t] - tot;
    if (base + 0 < N_NODES) row_ptr[base + 0] = excl + p0;
    if (base + 1 < N_NODES) row_ptr[base + 1] = excl + p1;
    if (base + 2 < N_NODES) row_ptr[base + 2] = excl + p2;
    if (base + 3 < N_NODES) row_ptr[base + 3] = excl + p3;
    if (t == 1023) bsums[blockIdx.x] = sd[1023];
}

// scan2: single thread over 13 block sums
__global__ void k_scan2(int* __restrict__ bsums, int nb) {
    if (threadIdx.x == 0 && blockIdx.x == 0) {
        int run = 0;
        for (int i = 0; i < nb; ++i) { int v = bsums[i]; bsums[i] = run; run += v; }
    }
}

// scan3: add block offsets, init cursor
__global__ void k_scan3(int* __restrict__ row_ptr, const int* __restrict__ bsums,
                        int* __restrict__ cursor) {
    int n = blockIdx.x * 256 + threadIdx.x;
    if (n < N_NODES) {
        int rp = row_ptr[n] + bsums[n >> 12];
        row_ptr[n] = rp;
        cursor[n] = rp;
    }
}

// ---------------- fill CSR buckets: (src, norm) packed in int2
__global__ void k_fill(const int* __restrict__ ei, const float* __restrict__ dis,
                       int* __restrict__ cursor, int2* __restrict__ edges) {
    int e = blockIdx.x * 256 + threadIdx.x;
    if (e < N_EDGES) {
        int uu = ei[e], vv = ei[N_EDGES + e];
        float nm = dis[uu] * dis[vv];
        int pos = atomicAdd(&cursor[vv], 1);
        edges[pos] = make_int2(uu, __float_as_int(nm));
    }
}

// ---------------- fp32 GEMM: C[M,64] = A[M,64] @ W[64,64] + bias, optional relu
// tile 128 rows, 8x4 microtile per thread, 256 threads
__global__ __launch_bounds__(256) void k_gemm(const float* __restrict__ A,
                                              const float* __restrict__ W,
                                              const float* __restrict__ bias,
                                              float* __restrict__ C,
                                              int M, int do_relu) {
    __shared__ float As[128][68];   // +4 pad keeps float4 alignment, breaks bank conflicts
    __shared__ float Bs[64][64];
    int t = threadIdx.x;
    int row0 = blockIdx.x * 128;
#pragma unroll
    for (int i = 0; i < 8; ++i) {
        int idx = t + i * 256;               // 0..2047
        int r = idx >> 4, c = (idx & 15) << 2;
        float4 val = make_float4(0.f, 0.f, 0.f, 0.f);
        if (row0 + r < M) val = *(const float4*)&A[(size_t)(row0 + r) * DIM + c];
        *(float4*)&As[r][c] = val;
    }
#pragma unroll
    for (int i = 0; i < 4; ++i) {
        int idx = t + i * 256;               // 0..1023
        int r = idx >> 4, c = (idx & 15) << 2;
        *(float4*)&Bs[r][c] = *(const float4*)&W[r * DIM + c];
    }
    __syncthreads();

    int r0 = (t >> 4) * 8;
    int c0 = (t & 15) * 4;
    float acc[8][4] = {};
#pragma unroll
    for (int k = 0; k < 64; k += 4) {
        float4 b0 = *(float4*)&Bs[k + 0][c0];
        float4 b1 = *(float4*)&Bs[k + 1][c0];
        float4 b2 = *(float4*)&Bs[k + 2][c0];
        float4 b3 = *(float4*)&Bs[k + 3][c0];
#pragma unroll
        for (int i = 0; i < 8; ++i) {
            float4 av = *(float4*)&As[r0 + i][k];
            acc[i][0] = fmaf(av.x, b0.x, fmaf(av.y, b1.x, fmaf(av.z, b2.x, fmaf(av.w, b3.x, acc[i][0]))));
            acc[i][1] = fmaf(av.x, b0.y, fmaf(av.y, b1.y, fmaf(av.z, b2.y, fmaf(av.w, b3.y, acc[i][1]))));
            acc[i][2] = fmaf(av.x, b0.z, fmaf(av.y, b1.z, fmaf(av.z, b2.z, fmaf(av.w, b3.z, acc[i][2]))));
            acc[i][3] = fmaf(av.x, b0.w, fmaf(av.y, b1.w, fmaf(av.z, b2.w, fmaf(av.w, b3.w, acc[i][3]))));
        }
    }

    float4 bv = *(const float4*)&bias[c0];
#pragma unroll
    for (int i = 0; i < 8; ++i) {
        int r = row0 + r0 + i;
        if (r < M) {
            float4 o;
            o.x = acc[i][0] + bv.x;
            o.y = acc[i][1] + bv.y;
            o.z = acc[i][2] + bv.z;
            o.w = acc[i][3] + bv.w;
            if (do_relu) {
                o.x = fmaxf(o.x, 0.f); o.y = fmaxf(o.y, 0.f);
                o.z = fmaxf(o.z, 0.f); o.w = fmaxf(o.w, 0.f);
            }
            *(float4*)&C[(size_t)r * DIM + c0] = o;
        }
    }
}

// ---------------- aggregation (gather form): X[n] = Henc[n] + sum_{e: v=n} norm_e * Henc[u_e]
// one wave per node, lane = feature
__global__ __launch_bounds__(256) void k_agg(const float* __restrict__ Henc,
                                             const int* __restrict__ row_ptr,
                                             const int* __restrict__ cnt,
                                             const int2* __restrict__ edges,
                                             float* __restrict__ X) {
    int node = (blockIdx.x << 2) + (threadIdx.x >> 6);
    int l = threadIdx.x & 63;
    if (node >= N_NODES) return;
    int start = row_ptr[node];
    int num = cnt[node];
    float acc = 0.f;
    for (int base = 0; base < num; base += 64) {
        int j = base + l;
        int2 er = make_int2(0, 0);
        if (j < num) er = edges[start + j];
        int lim = min(64, num - base);
        for (int kk = 0; kk < lim; ++kk) {
            int src = __shfl(er.x, kk, 64);
            float nm = __int_as_float(__shfl(er.y, kk, 64));
            acc = fmaf(nm, Henc[(size_t)src * DIM + l], acc);
        }
    }
    X[(size_t)node * DIM + l] = acc + Henc[(size_t)node * DIM + l];
}

// ---------------- readout part 1: column sums
__global__ __launch_bounds__(256) void k_colsum(const float* __restrict__ Hf,
                                                float* __restrict__ colsum) {
    int f = threadIdx.x & 63;
    int n0 = blockIdx.x * 4 + (threadIdx.x >> 6);
    float acc = 0.f;
    for (int n = n0; n < N_NODES; n += gridDim.x * 4)
        acc += Hf[(size_t)n * DIM + f];
    atomicAdd(&colsum[f], acc);
}

// ---------------- readout part 2: mean + dot with out_w + out_b
__global__ void k_out(const float* __restrict__ colsum, const float* __restrict__ out_w,
                      const float* __restrict__ out_b, float* __restrict__ out) {
    int f = threadIdx.x; // 64 threads
    float v = colsum[f] * (1.0f / (float)N_NODES) * out_w[f];
    for (int off = 32; off; off >>= 1) v += __shfl_down(v, off, 64);
    if (f == 0) out[0] = v + out_b[0];
}

extern "C" void kernel_launch(void* const* d_in, const int* in_sizes, int n_in,
                              void* d_out, int out_size, void* d_ws, size_t ws_size,
                              hipStream_t stream) {
    const float* H  = (const float*)d_in[0];
    const int*   ei = (const int*)d_in[1];
    // d_in[2] = E (edge features) is unused by the reference
    const float* enc_w[3] = { (const float*)d_in[3], (const float*)d_in[7],  (const float*)d_in[11] };
    const float* enc_b[3] = { (const float*)d_in[4], (const float*)d_in[8],  (const float*)d_in[12] };
    const float* upd_w[3] = { (const float*)d_in[5], (const float*)d_in[9],  (const float*)d_in[13] };
    const float* upd_b[3] = { (const float*)d_in[6], (const float*)d_in[10], (const float*)d_in[14] };
    const float* out_w = (const float*)d_in[15];
    const float* out_b = (const float*)d_in[16];
    float* out = (float*)d_out;

    // workspace carve-up (256B aligned)
    size_t off = 0;
    auto carve = [&](size_t bytes) {
        void* p = (char*)d_ws + off;
        off = (off + bytes + 255) & ~(size_t)255;
        return p;
    };
    int*   degu    = (int*)carve(N_NODES * 4);
    int*   cnt     = (int*)carve(N_NODES * 4);
    float* dis     = (float*)carve(N_NODES * 4);
    int*   row_ptr = (int*)carve(N_NODES * 4);
    int*   cursor  = (int*)carve(N_NODES * 4);
    int*   bsums   = (int*)carve(64 * 4);
    int2*  edges   = (int2*)carve((size_t)N_EDGES * 8);
    float* P0      = (float*)carve((size_t)N_NODES * DIM * 4);
    float* P1      = (float*)carve((size_t)N_NODES * DIM * 4);
    float* P2      = (float*)carve((size_t)N_NODES * DIM * 4);
    float* colsum  = (float*)carve(64 * 4);

    hipMemsetAsync(degu, 0, N_NODES * 4, stream);
    hipMemsetAsync(cnt, 0, N_NODES * 4, stream);
    hipMemsetAsync(colsum, 0, 64 * 4, stream);

    const int EB = (N_EDGES + 255) / 256;   // 4688
    const int NB = (N_NODES + 255) / 256;   // 196
    const int SCAN_NB = (N_NODES + 4095) / 4096; // 13

    k_hist<<<EB, 256, 0, stream>>>(ei, degu, cnt);
    k_dis<<<NB, 256, 0, stream>>>(degu, dis);
    k_scan1<<<SCAN_NB, 1024, 0, stream>>>(cnt, row_ptr, bsums);
    k_scan2<<<1, 64, 0, stream>>>(bsums, SCAN_NB);
    k_scan3<<<NB, 256, 0, stream>>>(row_ptr, bsums, cursor);
    k_fill<<<EB, 256, 0, stream>>>(ei, dis, cursor, edges);

    const int GB = (N_NODES + 127) / 128;   // 391
    const int AB = (N_NODES + 3) / 4;       // 12500

    const float* Hin = H;
    for (int i = 0; i < 3; ++i) {
        k_gemm<<<GB, 256, 0, stream>>>(Hin, enc_w[i], enc_b[i], P0, N_NODES, 0);
        k_agg<<<AB, 256, 0, stream>>>(P0, row_ptr, cnt, edges, P1);
        k_gemm<<<GB, 256, 0, stream>>>(P1, upd_w[i], upd_b[i], P2, N_NODES, 1);
        Hin = P2;
    }

    k_colsum<<<128, 256, 0, stream>>>(P2, colsum);
    k_out<<<1, 64, 0, stream>>>(colsum, out_w, out_b, out);
}

// Round 2
// 693.815 us; speedup vs baseline: 1.4419x; 1.4419x over previous
//
#include <hip/hip_runtime.h>
#include <hip/hip_bf16.h>

#define N_NODES 50000
#define N_EDGES 1200000
#define DIM 64

// ---------------- histogram + rank: degu (out-deg by u) for norm; cnt (in-deg by v)
// for CSR. The cnt atomic's return value IS the edge's rank within its bucket ->
// store it so the fill pass needs no atomics.
__global__ __launch_bounds__(256) void k_hist(const int* __restrict__ ei,
                                              int* __restrict__ degu,
                                              int* __restrict__ cnt,
                                              int* __restrict__ rank) {
    int base = (blockIdx.x * 256 + threadIdx.x) * 4;
    if (base + 3 < N_EDGES) {
        int4 u = *(const int4*)&ei[base];
        int4 v = *(const int4*)&ei[N_EDGES + base];
        atomicAdd(&degu[u.x], 1);
        atomicAdd(&degu[u.y], 1);
        atomicAdd(&degu[u.z], 1);
        atomicAdd(&degu[u.w], 1);
        int4 r;
        r.x = atomicAdd(&cnt[v.x], 1);
        r.y = atomicAdd(&cnt[v.y], 1);
        r.z = atomicAdd(&cnt[v.z], 1);
        r.w = atomicAdd(&cnt[v.w], 1);
        *(int4*)&rank[base] = r;
    } else {
        for (int e = base; e < N_EDGES; ++e) {
            atomicAdd(&degu[ei[e]], 1);
            rank[e] = atomicAdd(&cnt[ei[N_EDGES + e]], 1);
        }
    }
}

// ---------------- dis = (deg_u + 1)^-0.5
__global__ void k_dis(const int* __restrict__ degu, float* __restrict__ dis) {
    int n = blockIdx.x * 256 + threadIdx.x;
    if (n < N_NODES) dis[n] = rsqrtf((float)degu[n] + 1.0f);
}

// ---------------- 2-level exclusive scan of cnt -> row_ptr
__global__ __launch_bounds__(1024) void k_scan1(const int* __restrict__ cnt,
                                                int* __restrict__ row_ptr,
                                                int* __restrict__ bsums) {
    __shared__ int sd[1024];
    int t = threadIdx.x;
    int base = blockIdx.x * 4096 + t * 4;
    int v0 = (base + 0 < N_NODES) ? cnt[base + 0] : 0;
    int v1 = (base + 1 < N_NODES) ? cnt[base + 1] : 0;
    int v2 = (base + 2 < N_NODES) ? cnt[base + 2] : 0;
    int v3 = (base + 3 < N_NODES) ? cnt[base + 3] : 0;
    int p1 = v0, p2 = v0 + v1, p3 = v0 + v1 + v2;
    int tot = p3 + v3;
    sd[t] = tot;
    __syncthreads();
    for (int off = 1; off < 1024; off <<= 1) {
        int x = 0;
        if (t >= off) x = sd[t - off];
        __syncthreads();
        sd[t] += x;
        __syncthreads();
    }
    int excl = sd[t] - tot;
    if (base + 0 < N_NODES) row_ptr[base + 0] = excl;
    if (base + 1 < N_NODES) row_ptr[base + 1] = excl + p1;
    if (base + 2 < N_NODES) row_ptr[base + 2] = excl + p2;
    if (base + 3 < N_NODES) row_ptr[base + 3] = excl + p3;
    if (t == 1023) bsums[blockIdx.x] = sd[1023];
}

__global__ void k_scan2(int* __restrict__ bsums, int nb) {
    if (threadIdx.x == 0 && blockIdx.x == 0) {
        int run = 0;
        for (int i = 0; i < nb; ++i) { int v = bsums[i]; bsums[i] = run; run += v; }
    }
}

__global__ void k_scan3(int* __restrict__ row_ptr, const int* __restrict__ bsums) {
    int n = blockIdx.x * 256 + threadIdx.x;
    if (n < N_NODES) row_ptr[n] += bsums[n >> 12];
}

// ---------------- fill CSR buckets (no atomics: rank precomputed)
__global__ __launch_bounds__(256) void k_fill(const int* __restrict__ ei,
                                              const float* __restrict__ dis,
                                              const int* __restrict__ row_ptr,
                                              const int* __restrict__ rank,
                                              int2* __restrict__ edges) {
    int e = blockIdx.x * 256 + threadIdx.x;
    if (e < N_EDGES) {
        int uu = ei[e], vv = ei[N_EDGES + e];
        float nm = dis[uu] * dis[vv];
        edges[row_ptr[vv] + rank[e]] = make_int2(uu, __float_as_int(nm));
    }
}

// ---------------- fp32 GEMM: C[M,64] = A[M,64] @ W[64,64] + bias, optional relu
// 64-row tile, 4x4 microtile, 256 threads. VGPR ~64, LDS 33 KB -> good occupancy.
__global__ __launch_bounds__(256) void k_gemm(const float* __restrict__ A,
                                              const float* __restrict__ W,
                                              const float* __restrict__ bias,
                                              float* __restrict__ C,
                                              int M, int do_relu) {
    __shared__ float As[64][68];   // +4 pad: float4-aligned, conflict-free
    __shared__ float Bs[64][64];
    int t = threadIdx.x;
    int row0 = blockIdx.x * 64;
#pragma unroll
    for (int i = 0; i < 4; ++i) {
        int idx = t + i * 256;               // 0..1023
        int r = idx >> 4, c = (idx & 15) << 2;
        float4 val = make_float4(0.f, 0.f, 0.f, 0.f);
        if (row0 + r < M) val = *(const float4*)&A[(size_t)(row0 + r) * DIM + c];
        *(float4*)&As[r][c] = val;
        *(float4*)&Bs[r][c] = *(const float4*)&W[r * DIM + c];
    }
    __syncthreads();

    int r0 = (t >> 4) * 4;
    int c0 = (t & 15) * 4;
    float acc[4][4] = {};
#pragma unroll
    for (int k = 0; k < 64; k += 4) {
        float4 b0 = *(float4*)&Bs[k + 0][c0];
        float4 b1 = *(float4*)&Bs[k + 1][c0];
        float4 b2 = *(float4*)&Bs[k + 2][c0];
        float4 b3 = *(float4*)&Bs[k + 3][c0];
#pragma unroll
        for (int i = 0; i < 4; ++i) {
            float4 av = *(float4*)&As[r0 + i][k];
            acc[i][0] = fmaf(av.x, b0.x, fmaf(av.y, b1.x, fmaf(av.z, b2.x, fmaf(av.w, b3.x, acc[i][0]))));
            acc[i][1] = fmaf(av.x, b0.y, fmaf(av.y, b1.y, fmaf(av.z, b2.y, fmaf(av.w, b3.y, acc[i][1]))));
            acc[i][2] = fmaf(av.x, b0.z, fmaf(av.y, b1.z, fmaf(av.z, b2.z, fmaf(av.w, b3.z, acc[i][2]))));
            acc[i][3] = fmaf(av.x, b0.w, fmaf(av.y, b1.w, fmaf(av.z, b2.w, fmaf(av.w, b3.w, acc[i][3]))));
        }
    }

    float4 bv = *(const float4*)&bias[c0];
#pragma unroll
    for (int i = 0; i < 4; ++i) {
        int r = row0 + r0 + i;
        if (r < M) {
            float4 o;
            o.x = acc[i][0] + bv.x;
            o.y = acc[i][1] + bv.y;
            o.z = acc[i][2] + bv.z;
            o.w = acc[i][3] + bv.w;
            if (do_relu) {
                o.x = fmaxf(o.x, 0.f); o.y = fmaxf(o.y, 0.f);
                o.z = fmaxf(o.z, 0.f); o.w = fmaxf(o.w, 0.f);
            }
            *(float4*)&C[(size_t)r * DIM + c0] = o;
        }
    }
}

// ---------------- aggregation (gather): X[n] = Henc[n] + sum_{e: v=n} norm_e * Henc[u_e]
__global__ __launch_bounds__(256) void k_agg(const float* __restrict__ Henc,
                                             const int* __restrict__ row_ptr,
                                             const int* __restrict__ cnt,
                                             const int2* __restrict__ edges,
                                             float* __restrict__ X) {
    int node = (blockIdx.x << 2) + (threadIdx.x >> 6);
    int l = threadIdx.x & 63;
    if (node >= N_NODES) return;
    int start = row_ptr[node];
    int num = cnt[node];
    float acc = 0.f;
    for (int base = 0; base < num; base += 64) {
        int j = base + l;
        int2 er = make_int2(0, 0);
        if (j < num) er = edges[start + j];
        int lim = min(64, num - base);
        for (int kk = 0; kk < lim; ++kk) {
            int src = __shfl(er.x, kk, 64);
            float nm = __int_as_float(__shfl(er.y, kk, 64));
            acc = fmaf(nm, Henc[(size_t)src * DIM + l], acc);
        }
    }
    X[(size_t)node * DIM + l] = acc + Henc[(size_t)node * DIM + l];
}

// ---------------- readout
__global__ __launch_bounds__(256) void k_colsum(const float* __restrict__ Hf,
                                                float* __restrict__ colsum) {
    int f = threadIdx.x & 63;
    int n0 = blockIdx.x * 4 + (threadIdx.x >> 6);
    float acc = 0.f;
    for (int n = n0; n < N_NODES; n += gridDim.x * 4)
        acc += Hf[(size_t)n * DIM + f];
    atomicAdd(&colsum[f], acc);
}

__global__ void k_out(const float* __restrict__ colsum, const float* __restrict__ out_w,
                      const float* __restrict__ out_b, float* __restrict__ out) {
    int f = threadIdx.x; // 64 threads
    float v = colsum[f] * (1.0f / (float)N_NODES) * out_w[f];
    for (int off = 32; off; off >>= 1) v += __shfl_down(v, off, 64);
    if (f == 0) out[0] = v + out_b[0];
}

extern "C" void kernel_launch(void* const* d_in, const int* in_sizes, int n_in,
                              void* d_out, int out_size, void* d_ws, size_t ws_size,
                              hipStream_t stream) {
    const float* H  = (const float*)d_in[0];
    const int*   ei = (const int*)d_in[1];
    const float* enc_w[3] = { (const float*)d_in[3], (const float*)d_in[7],  (const float*)d_in[11] };
    const float* enc_b[3] = { (const float*)d_in[4], (const float*)d_in[8],  (const float*)d_in[12] };
    const float* upd_w[3] = { (const float*)d_in[5], (const float*)d_in[9],  (const float*)d_in[13] };
    const float* upd_b[3] = { (const float*)d_in[6], (const float*)d_in[10], (const float*)d_in[14] };
    const float* out_w = (const float*)d_in[15];
    const float* out_b = (const float*)d_in[16];
    float* out = (float*)d_out;

    size_t off = 0;
    auto carve = [&](size_t bytes) {
        void* p = (char*)d_ws + off;
        off = (off + bytes + 255) & ~(size_t)255;
        return p;
    };
    int*   degu    = (int*)carve(N_NODES * 4);
    int*   cnt     = (int*)carve(N_NODES * 4);
    float* dis     = (float*)carve(N_NODES * 4);
    int*   row_ptr = (int*)carve(N_NODES * 4);
    int*   bsums   = (int*)carve(64 * 4);
    int*   rank    = (int*)carve((size_t)N_EDGES * 4);
    int2*  edges   = (int2*)carve((size_t)N_EDGES * 8);
    float* P0      = (float*)carve((size_t)N_NODES * DIM * 4);
    float* P1      = (float*)carve((size_t)N_NODES * DIM * 4);
    float* P2      = (float*)carve((size_t)N_NODES * DIM * 4);
    float* colsum  = (float*)carve(64 * 4);

    hipMemsetAsync(degu, 0, N_NODES * 4, stream);
    hipMemsetAsync(cnt, 0, N_NODES * 4, stream);
    hipMemsetAsync(colsum, 0, 64 * 4, stream);

    const int EB  = (N_EDGES + 255) / 256;          // 4688
    const int EB4 = (N_EDGES / 4 + 255) / 256;      // 1172
    const int NB  = (N_NODES + 255) / 256;          // 196
    const int SCAN_NB = (N_NODES + 4095) / 4096;    // 13

    k_hist<<<EB4, 256, 0, stream>>>(ei, degu, cnt, rank);
    k_dis<<<NB, 256, 0, stream>>>(degu, dis);
    k_scan1<<<SCAN_NB, 1024, 0, stream>>>(cnt, row_ptr, bsums);
    k_scan2<<<1, 64, 0, stream>>>(bsums, SCAN_NB);
    k_scan3<<<NB, 256, 0, stream>>>(row_ptr, bsums);
    k_fill<<<EB, 256, 0, stream>>>(ei, dis, row_ptr, rank, edges);

    const int GB = (N_NODES + 63) / 64;             // 782
    const int AB = (N_NODES + 3) / 4;               // 12500

    const float* Hin = H;
    for (int i = 0; i < 3; ++i) {
        k_gemm<<<GB, 256, 0, stream>>>(Hin, enc_w[i], enc_b[i], P0, N_NODES, 0);
        k_agg<<<AB, 256, 0, stream>>>(P0, row_ptr, cnt, edges, P1);
        k_gemm<<<GB, 256, 0, stream>>>(P1, upd_w[i], upd_b[i], P2, N_NODES, 1);
        Hin = P2;
    }

    k_colsum<<<128, 256, 0, stream>>>(P2, colsum);
    k_out<<<1, 64, 0, stream>>>(colsum, out_w, out_b, out);
}

// Round 3
// 559.642 us; speedup vs baseline: 1.7876x; 1.2397x over previous
//
#include <hip/hip_runtime.h>
#include <hip/hip_bf16.h>

#define N_NODES 50000
#define N_EDGES 1200000
#define DIM 64

// ---------------- histogram + rank. 1 edge/thread: max memory-level parallelism,
// atomics are fabric-transaction-bound (~24 G/s), so more waves in flight = better.
__global__ __launch_bounds__(256) void k_hist(const int* __restrict__ ei,
                                              int* __restrict__ degu,
                                              int* __restrict__ cnt,
                                              int* __restrict__ rank) {
    int e = blockIdx.x * 256 + threadIdx.x;
    if (e < N_EDGES) {
        atomicAdd(&degu[ei[e]], 1);                       // non-returning
        rank[e] = atomicAdd(&cnt[ei[N_EDGES + e]], 1);    // returning (rank in bucket)
    }
}

// ---------------- dis = (deg_u + 1)^-0.5
__global__ void k_dis(const int* __restrict__ degu, float* __restrict__ dis) {
    int n = blockIdx.x * 256 + threadIdx.x;
    if (n < N_NODES) dis[n] = rsqrtf((float)degu[n] + 1.0f);
}

// ---------------- 2-level exclusive scan of cnt -> row_ptr
__global__ __launch_bounds__(1024) void k_scan1(const int* __restrict__ cnt,
                                                int* __restrict__ row_ptr,
                                                int* __restrict__ bsums) {
    __shared__ int sd[1024];
    int t = threadIdx.x;
    int base = blockIdx.x * 4096 + t * 4;
    int v0 = (base + 0 < N_NODES) ? cnt[base + 0] : 0;
    int v1 = (base + 1 < N_NODES) ? cnt[base + 1] : 0;
    int v2 = (base + 2 < N_NODES) ? cnt[base + 2] : 0;
    int v3 = (base + 3 < N_NODES) ? cnt[base + 3] : 0;
    int p1 = v0, p2 = v0 + v1, p3 = v0 + v1 + v2;
    int tot = p3 + v3;
    sd[t] = tot;
    __syncthreads();
    for (int off = 1; off < 1024; off <<= 1) {
        int x = 0;
        if (t >= off) x = sd[t - off];
        __syncthreads();
        sd[t] += x;
        __syncthreads();
    }
    int excl = sd[t] - tot;
    if (base + 0 < N_NODES) row_ptr[base + 0] = excl;
    if (base + 1 < N_NODES) row_ptr[base + 1] = excl + p1;
    if (base + 2 < N_NODES) row_ptr[base + 2] = excl + p2;
    if (base + 3 < N_NODES) row_ptr[base + 3] = excl + p3;
    if (t == 1023) bsums[blockIdx.x] = sd[1023];
}

__global__ void k_scan2(int* __restrict__ bsums, int nb) {
    if (threadIdx.x == 0 && blockIdx.x == 0) {
        int run = 0;
        for (int i = 0; i < nb; ++i) { int v = bsums[i]; bsums[i] = run; run += v; }
    }
}

__global__ void k_scan3(int* __restrict__ row_ptr, const int* __restrict__ bsums) {
    int n = blockIdx.x * 256 + threadIdx.x;
    if (n < N_NODES) row_ptr[n] += bsums[n >> 12];
}

// ---------------- fill CSR buckets (no atomics: rank precomputed).
// Store u*DIM so agg needs no per-edge shift.
__global__ __launch_bounds__(256) void k_fill(const int* __restrict__ ei,
                                              const float* __restrict__ dis,
                                              const int* __restrict__ row_ptr,
                                              const int* __restrict__ rank,
                                              int2* __restrict__ edges) {
    int e = blockIdx.x * 256 + threadIdx.x;
    if (e < N_EDGES) {
        int uu = ei[e], vv = ei[N_EDGES + e];
        float nm = dis[uu] * dis[vv];
        edges[row_ptr[vv] + rank[e]] = make_int2(uu * DIM, __float_as_int(nm));
    }
}

// ---------------- fp32 GEMM: C[M,64] = A[M,64] @ W[64,64] + bias
// mode 0: plain store; 1: relu+store; 2: relu + column-sum only (no store).
__global__ __launch_bounds__(256) void k_gemm(const float* __restrict__ A,
                                              const float* __restrict__ W,
                                              const float* __restrict__ bias,
                                              float* __restrict__ C,
                                              int M, int mode,
                                              float* __restrict__ colsum) {
    __shared__ float As[64][68];   // +4 pad: float4-aligned, conflict-free
    __shared__ float Bs[64][64];
    int t = threadIdx.x;
    int row0 = blockIdx.x * 64;
#pragma unroll
    for (int i = 0; i < 4; ++i) {
        int idx = t + i * 256;               // 0..1023
        int r = idx >> 4, c = (idx & 15) << 2;
        float4 val = make_float4(0.f, 0.f, 0.f, 0.f);
        if (row0 + r < M) val = *(const float4*)&A[(size_t)(row0 + r) * DIM + c];
        *(float4*)&As[r][c] = val;
        *(float4*)&Bs[r][c] = *(const float4*)&W[r * DIM + c];
    }
    __syncthreads();

    int r0 = (t >> 4) * 4;
    int c0 = (t & 15) * 4;
    float acc[4][4] = {};
#pragma unroll
    for (int k = 0; k < 64; k += 4) {
        float4 b0 = *(float4*)&Bs[k + 0][c0];
        float4 b1 = *(float4*)&Bs[k + 1][c0];
        float4 b2 = *(float4*)&Bs[k + 2][c0];
        float4 b3 = *(float4*)&Bs[k + 3][c0];
#pragma unroll
        for (int i = 0; i < 4; ++i) {
            float4 av = *(float4*)&As[r0 + i][k];
            acc[i][0] = fmaf(av.x, b0.x, fmaf(av.y, b1.x, fmaf(av.z, b2.x, fmaf(av.w, b3.x, acc[i][0]))));
            acc[i][1] = fmaf(av.x, b0.y, fmaf(av.y, b1.y, fmaf(av.z, b2.y, fmaf(av.w, b3.y, acc[i][1]))));
            acc[i][2] = fmaf(av.x, b0.z, fmaf(av.y, b1.z, fmaf(av.z, b2.z, fmaf(av.w, b3.z, acc[i][2]))));
            acc[i][3] = fmaf(av.x, b0.w, fmaf(av.y, b1.w, fmaf(av.z, b2.w, fmaf(av.w, b3.w, acc[i][3]))));
        }
    }

    float4 bv = *(const float4*)&bias[c0];
    float csum[4] = {0.f, 0.f, 0.f, 0.f};
#pragma unroll
    for (int i = 0; i < 4; ++i) {
        int r = row0 + r0 + i;
        if (r < M) {
            float4 o;
            o.x = acc[i][0] + bv.x;
            o.y = acc[i][1] + bv.y;
            o.z = acc[i][2] + bv.z;
            o.w = acc[i][3] + bv.w;
            if (mode != 0) {
                o.x = fmaxf(o.x, 0.f); o.y = fmaxf(o.y, 0.f);
                o.z = fmaxf(o.z, 0.f); o.w = fmaxf(o.w, 0.f);
            }
            if (mode != 2) {
                *(float4*)&C[(size_t)r * DIM + c0] = o;
            } else {
                csum[0] += o.x; csum[1] += o.y; csum[2] += o.z; csum[3] += o.w;
            }
        }
    }
    if (mode == 2) {
        // block-level column reduction into colsum (reuse As as scratch)
        float* red = &As[0][0];
        __syncthreads();
        *(float4*)&red[(t >> 4) * 64 + c0] = make_float4(csum[0], csum[1], csum[2], csum[3]);
        __syncthreads();
        if (t < 64) {
            float s = 0.f;
#pragma unroll
            for (int g = 0; g < 16; ++g) s += red[g * 64 + t];
            atomicAdd(&colsum[t], s);
        }
    }
}

// ---------------- aggregation (gather): X[n] = Henc[n] + sum_{e: v=n} norm_e * Henc[u_e]
// One wave per node, lane = feature. Edge records staged in LDS (uniform-address
// broadcast reads), 8 independent row-loads in flight per iteration.
__global__ __launch_bounds__(256) void k_agg(const float* __restrict__ Henc,
                                             const int* __restrict__ row_ptr,
                                             const int* __restrict__ cnt,
                                             const int2* __restrict__ edges,
                                             float* __restrict__ X) {
    __shared__ int2 se[4][64];
    int w = threadIdx.x >> 6;
    int l = threadIdx.x & 63;
    int node = (blockIdx.x << 2) + w;
    if (node >= N_NODES) return;
    int start = row_ptr[node];
    int num = cnt[node];
    float acc = 0.f;
    for (int base = 0; base < num; base += 64) {
        int lim = min(64, num - base);
        if (l < lim) se[w][l] = edges[start + base + l];
        __builtin_amdgcn_wave_barrier();   // wave-synchronous LDS: in-order DS + lgkmcnt
        int kk = 0;
        for (; kk + 8 <= lim; kk += 8) {
            int2 e0 = se[w][kk + 0];
            int2 e1 = se[w][kk + 1];
            int2 e2 = se[w][kk + 2];
            int2 e3 = se[w][kk + 3];
            int2 e4 = se[w][kk + 4];
            int2 e5 = se[w][kk + 5];
            int2 e6 = se[w][kk + 6];
            int2 e7 = se[w][kk + 7];
            float h0 = Henc[(size_t)(e0.x + l)];
            float h1 = Henc[(size_t)(e1.x + l)];
            float h2 = Henc[(size_t)(e2.x + l)];
            float h3 = Henc[(size_t)(e3.x + l)];
            float h4 = Henc[(size_t)(e4.x + l)];
            float h5 = Henc[(size_t)(e5.x + l)];
            float h6 = Henc[(size_t)(e6.x + l)];
            float h7 = Henc[(size_t)(e7.x + l)];
            acc = fmaf(__int_as_float(e0.y), h0, acc);
            acc = fmaf(__int_as_float(e1.y), h1, acc);
            acc = fmaf(__int_as_float(e2.y), h2, acc);
            acc = fmaf(__int_as_float(e3.y), h3, acc);
            acc = fmaf(__int_as_float(e4.y), h4, acc);
            acc = fmaf(__int_as_float(e5.y), h5, acc);
            acc = fmaf(__int_as_float(e6.y), h6, acc);
            acc = fmaf(__int_as_float(e7.y), h7, acc);
        }
        for (; kk < lim; ++kk) {
            int2 e0 = se[w][kk];
            acc = fmaf(__int_as_float(e0.y), Henc[(size_t)(e0.x + l)], acc);
        }
        __builtin_amdgcn_wave_barrier();
    }
    X[(size_t)node * DIM + l] = acc + Henc[(size_t)node * DIM + l];
}

// ---------------- readout: mean + dot with out_w + out_b
__global__ void k_out(const float* __restrict__ colsum, const float* __restrict__ out_w,
                      const float* __restrict__ out_b, float* __restrict__ out) {
    int f = threadIdx.x; // 64 threads
    float v = colsum[f] * (1.0f / (float)N_NODES) * out_w[f];
    for (int off = 32; off; off >>= 1) v += __shfl_down(v, off, 64);
    if (f == 0) out[0] = v + out_b[0];
}

extern "C" void kernel_launch(void* const* d_in, const int* in_sizes, int n_in,
                              void* d_out, int out_size, void* d_ws, size_t ws_size,
                              hipStream_t stream) {
    const float* H  = (const float*)d_in[0];
    const int*   ei = (const int*)d_in[1];
    const float* enc_w[3] = { (const float*)d_in[3], (const float*)d_in[7],  (const float*)d_in[11] };
    const float* enc_b[3] = { (const float*)d_in[4], (const float*)d_in[8],  (const float*)d_in[12] };
    const float* upd_w[3] = { (const float*)d_in[5], (const float*)d_in[9],  (const float*)d_in[13] };
    const float* upd_b[3] = { (const float*)d_in[6], (const float*)d_in[10], (const float*)d_in[14] };
    const float* out_w = (const float*)d_in[15];
    const float* out_b = (const float*)d_in[16];
    float* out = (float*)d_out;

    size_t off = 0;
    auto carve = [&](size_t bytes) {
        void* p = (char*)d_ws + off;
        off = (off + bytes + 255) & ~(size_t)255;
        return p;
    };
    // zero-region first (single memset): degu | cnt | colsum
    int*   degu    = (int*)carve(N_NODES * 4);
    int*   cnt     = (int*)carve(N_NODES * 4);
    float* colsum  = (float*)carve(64 * 4);
    size_t zero_bytes = off;
    float* dis     = (float*)carve(N_NODES * 4);
    int*   row_ptr = (int*)carve(N_NODES * 4);
    int*   bsums   = (int*)carve(64 * 4);
    int*   rank    = (int*)carve((size_t)N_EDGES * 4);
    int2*  edges   = (int2*)carve((size_t)N_EDGES * 8);
    float* P0      = (float*)carve((size_t)N_NODES * DIM * 4);
    float* P1      = (float*)carve((size_t)N_NODES * DIM * 4);
    float* P2      = (float*)carve((size_t)N_NODES * DIM * 4);

    hipMemsetAsync(degu, 0, zero_bytes, stream);

    const int EB = (N_EDGES + 255) / 256;          // 4688
    const int NB = (N_NODES + 255) / 256;          // 196
    const int SCAN_NB = (N_NODES + 4095) / 4096;   // 13

    k_hist<<<EB, 256, 0, stream>>>(ei, degu, cnt, rank);
    k_dis<<<NB, 256, 0, stream>>>(degu, dis);
    k_scan1<<<SCAN_NB, 1024, 0, stream>>>(cnt, row_ptr, bsums);
    k_scan2<<<1, 64, 0, stream>>>(bsums, SCAN_NB);
    k_scan3<<<NB, 256, 0, stream>>>(row_ptr, bsums);
    k_fill<<<EB, 256, 0, stream>>>(ei, dis, row_ptr, rank, edges);

    const int GB = (N_NODES + 63) / 64;            // 782
    const int AB = (N_NODES + 3) / 4;              // 12500

    const float* Hin = H;
    for (int i = 0; i < 3; ++i) {
        k_gemm<<<GB, 256, 0, stream>>>(Hin, enc_w[i], enc_b[i], P0, N_NODES, 0, nullptr);
        k_agg<<<AB, 256, 0, stream>>>(P0, row_ptr, cnt, edges, P1);
        int mode = (i == 2) ? 2 : 1;
        k_gemm<<<GB, 256, 0, stream>>>(P1, upd_w[i], upd_b[i], P2, N_NODES, mode, colsum);
        Hin = P2;
    }

    k_out<<<1, 64, 0, stream>>>(colsum, out_w, out_b, out);
}